// Round 9
// baseline (268.083 us; speedup 1.0000x reference)
//
#include <hip/hip_runtime.h>

#define DEVFN __device__ __forceinline__

typedef unsigned short u16;
typedef __attribute__((ext_vector_type(8))) unsigned short u16x8;
typedef __attribute__((ext_vector_type(4))) unsigned short u16x4;
typedef __attribute__((ext_vector_type(8))) __bf16 bf16x8;
typedef __attribute__((ext_vector_type(4))) float f32x4;

// ---------- helpers ----------
DEVFN u16 f2bf_hw(float f) {  // hardware RNE convert (single v_cvt)
    return __builtin_bit_cast(u16, (__bf16)f);
}

DEVFN float bf2f(u16 h) {
    unsigned u = (unsigned)h << 16;
    return __builtin_bit_cast(float, u);
}

DEVFN bf16x8 ldfrag(const u16* p) {
    return __builtin_bit_cast(bf16x8, *(const u16x8*)p);
}

DEVFN f32x4 mfma16(bf16x8 a, bf16x8 b, f32x4 c) {
    return __builtin_amdgcn_mfma_f32_16x16x32_bf16(a, b, c, 0, 0, 0);
}

// async global->LDS, 16B per lane; l must be the wave-uniform base.
// The GLOBAL source address is per-lane (guide §5) -> row-gather OK.
DEVFN void async16(const u16* g, u16* l) {
    __builtin_amdgcn_global_load_lds(
        (const __attribute__((address_space(1))) void*)g,
        (__attribute__((address_space(3))) void*)l, 16, 0, 0);
}

// ---------- fp32->bf16 converts + mask compaction, ONE dispatch ----------
__global__ __launch_bounds__(256) void conv_all(const float* __restrict__ y,
                                                const float* __restrict__ w0,
                                                const float* __restrict__ w1,
                                                const float* __restrict__ w2,
                                                const float* __restrict__ w3,
                                                u16* __restrict__ yb,
                                                u16* __restrict__ wb,
                                                const int* __restrict__ mask,
                                                int* __restrict__ idx,
                                                int* __restrict__ cnt) {
    const int b = blockIdx.x;
    if (b >= 12288) {
        const int wave = threadIdx.x >> 6, lane = threadIdx.x & 63;
        for (int bb = wave; bb < 8; bb += 4) {
            const int* m = mask + bb * 1024;
            int* ib = idx + bb * 1024;
            int base = 0;
            for (int t = 0; t < 16; ++t) {
                const int pos = t * 64 + lane;
                const int valid = (m[pos] == 0) ? 1 : 0;
                const unsigned long long bal = __ballot(valid);
                const int pre = __popcll(bal & ((1ull << lane) - 1ull));
                if (valid) ib[base + pre] = pos;
                base += (int)__popcll(bal);
            }
            if (lane == 0) cnt[bb] = base;
            for (int i = base + lane; i < 1024; i += 64) ib[i] = 0;  // safe pad
        }
        return;
    }
    const float* src;
    u16* dst;
    int i;
    if (b < 8192) {
        src = y; dst = yb;
        i = b * 1024 + threadIdx.x * 4;
    } else {
        const int g = (b - 8192) >> 10;
        src = g == 0 ? w0 : (g == 1 ? w1 : (g == 2 ? w2 : w3));
        dst = wb + (size_t)g * 1024 * 1024;
        i = ((b - 8192) & 1023) * 1024 + threadIdx.x * 4;
    }
    const float4 v = *(const float4*)&src[i];
    u16x4 o;
    o.x = f2bf_hw(v.x); o.y = f2bf_hw(v.y);
    o.z = f2bf_hw(v.z); o.w = f2bf_hw(v.w);
    *(u16x4*)&dst[i] = o;
}

// ---------- Q + compacted-KV GEMM: legacy 128^2 engine, now DOUBLE-BUFFERED --
// Round-9: r8 proved conflicts weren't the critical path (0 conflicts, only
// -1.7 us). The remaining stall is structural: stage -> __syncthreads per
// 32-K step forces a full vmcnt(0) drain 32x/tile (MfmaUtil 23 + VALUBusy
// 12 = 65% idle). Fix: LDS double-buffer (2x16 KiB = 32 KiB/block, still
// 4 blocks/CU at 128 KiB) + stage-ahead-2 + counted vmcnt(4) + raw barriers.
// NOTE this differs from the guide's m99/m100 "dbuf is null" case: that
// structure already staged ahead; ours drains to ZERO each step.
//
// Per-iter ledger (t = K-step, buf = t&1):
//   [ds_read 8 frags of buf; 16 MFMA]            <- compiler lgkm-orders
//   s_barrier                                    <- every wave consumed buf[t]
//   STAGE t+2 -> buf[t]                          <- WAR-safe by that barrier
//   vmcnt(4)                                     <- leaves only t+2's 4 ops;
//                                                   t+1 (issued iter t-1) is
//                                                   resident
//   s_barrier                                    <- publishes t+1 to all waves
// Prologue: STAGE k0->buf0, k1->buf1; vmcnt(4); barrier. Tail t>=30: vmcnt(0).
// ds_reads can't be compiler-hoisted above the vmcnt asm ("memory" clobber
// orders memory ops; rule-18 only bites register-only MFMA).
// Decode/swizzle/accumulation order identical to r8 -> bit-identical output.
//   items 0..511   : Q-type  = A @ Bt^T  (64 mtiles x 8 ntiles, n-fast)
//   items 512..1535: KV = y[idx] @ [Wk;Wv]^T per batch (alive iff m0 < cn)
// Also reused for M-proj: grid=512 -> pure Q-type path (A=attb, Bt=Wm).
__global__ __launch_bounds__(256, 4) void gemm_qkv(const u16* __restrict__ A,
                                                   const u16* __restrict__ Wq,
                                                   const u16* __restrict__ Wkv,
                                                   const float* __restrict__ bq,
                                                   const float* __restrict__ bk,
                                                   const float* __restrict__ bv,
                                                   u16* __restrict__ qb,
                                                   u16* __restrict__ kb,
                                                   u16* __restrict__ vb,
                                                   const int* __restrict__ idxb,
                                                   const int* __restrict__ cntb) {
    const int K = 1024;
    __shared__ u16 lA[2][128 * 32];
    __shared__ u16 lB[2][128 * 32];
    const int tid = threadIdx.x;
    const int wave = tid >> 6, lane = tid & 63;
    const int quad = lane >> 4, l16 = lane & 15;
    const int wm = (wave >> 1) * 64, wn = (wave & 1) * 64;
    const int srow = tid >> 2;
    // pre-swizzled source slot (write side of the r8 slot-XOR)
    const int scol = (((tid & 3) ^ ((srow >> 1) & 3))) * 8;
    // ---- static decode (n-fast everywhere, Q first then KV batches) ----
    const int item = blockIdx.x;
    int m0, n0, rowbase = 0;
    const u16* Bt;
    const float *bp0, *bp1;
    u16 *cp0, *cp1;
    const int* ib = nullptr;
    if (item < 512) {  // Q: m = item>>3, n = item&7
        m0 = (item >> 3) * 128;
        n0 = (item & 7) * 128;
        Bt = Wq; bp0 = bq; bp1 = bq; cp0 = qb; cp1 = qb;
    } else {  // KV: batch-major, then m, n fastest
        const int t = item - 512;
        const int b = t >> 7, rem = t & 127;
        const int mb = rem >> 4, nb = rem & 15;
        const int cn = cntb[b];
        m0 = mb * 128;
        if (m0 >= cn) return;  // dead tile (rows >= ceil128(cn) never read)
        n0 = nb * 128;
        rowbase = b * 1024;
        ib = idxb + b * 1024;
        Bt = Wkv; bp0 = bk; bp1 = bv; cp0 = kb; cp1 = vb;
    }
    int r0 = m0 + srow, r1 = m0 + 64 + srow;
    if (ib) { r0 = ib[r0]; r1 = ib[r1]; }  // gather compacted A rows
    const u16* Ag0 = A + (size_t)(rowbase + r0) * K + scol;
    const u16* Ag1 = A + (size_t)(rowbase + r1) * K + scol;
    const u16* Bg0 = Bt + (size_t)(n0 + srow) * K + scol;
    const u16* Bg1 = Bt + (size_t)(n0 + 64 + srow) * K + scol;
    // read-side swizzled slot (r8): (row>>1)&3 == (l16>>1)&3 for our rows
    const int sl = (quad ^ ((l16 >> 1) & 3)) * 8;

#define STAGE(kof, bf)                                     \
    do {                                                   \
        async16(Ag0 + (kof), &lA[bf][wave * 512]);         \
        async16(Ag1 + (kof), &lA[bf][2048 + wave * 512]);  \
        async16(Bg0 + (kof), &lB[bf][wave * 512]);         \
        async16(Bg1 + (kof), &lB[bf][2048 + wave * 512]);  \
    } while (0)

    f32x4 acc[4][4] = {};

    // prologue: k-step 0 -> buf0, k-step 1 -> buf1; wait step0 resident
    STAGE(0, 0);
    STAGE(32, 1);
    asm volatile("s_waitcnt vmcnt(4)" ::: "memory");
    __builtin_amdgcn_s_barrier();

    for (int t = 0; t < 32; ++t) {
        const int buf = t & 1;
        bf16x8 af[4], bfr[4];
        #pragma unroll
        for (int i = 0; i < 4; ++i)
            af[i] = ldfrag(&lA[buf][(wm + i * 16 + l16) * 32 + sl]);
        #pragma unroll
        for (int i = 0; i < 4; ++i)
            bfr[i] = ldfrag(&lB[buf][(wn + i * 16 + l16) * 32 + sl]);
        #pragma unroll
        for (int mi = 0; mi < 4; ++mi)
            #pragma unroll
            for (int ni = 0; ni < 4; ++ni)
                acc[mi][ni] = mfma16(af[mi], bfr[ni], acc[mi][ni]);
        // all this wave's reads of buf[t] are consumed by the MFMAs above
        __builtin_amdgcn_s_barrier();   // -> ALL waves done with buf[t]
        if (t + 2 < 32) STAGE((t + 2) * 32, buf);
        if (t < 30)
            asm volatile("s_waitcnt vmcnt(4)" ::: "memory");  // t+1 resident
        else
            asm volatile("s_waitcnt vmcnt(0)" ::: "memory");
        __builtin_amdgcn_s_barrier();   // publish t+1
    }
#undef STAGE
    // epilogue: bias + bf16 store; col>>10 selects {q} or {k,v}
    #pragma unroll
    for (int mi = 0; mi < 4; ++mi) {
        #pragma unroll
        for (int ni = 0; ni < 4; ++ni) {
            const int col = n0 + wn + ni * 16 + l16;
            const int cs = col >> 10;
            const int c = col & 1023;
            const float* bp = cs == 0 ? bp0 : bp1;
            u16* cp = cs == 0 ? cp0 : cp1;
            const float bb = bp[c];
            #pragma unroll
            for (int r = 0; r < 4; ++r) {
                const int row = m0 + wm + mi * 16 + quad * 4 + r;
                cp[(size_t)(rowbase + row) * 1024 + c] =
                    f2bf_hw(acc[mi][ni][r] + bb);
            }
        }
    }
}

// ---------- flash attention over COMPACTED K/V (dense rows) ----------
__global__ __launch_bounds__(256) void attn(const u16* __restrict__ qb,
                                            const u16* __restrict__ kb,
                                            const u16* __restrict__ vb,
                                            const int* __restrict__ cntb,
                                            u16* __restrict__ attb) {
    const int lin = blockIdx.x;
    const int xcd = lin & 7, slot = lin >> 3;          // slot 0..127
    const int bh = xcd * 16 + (slot >> 3);
    const int q0 = (slot & 7) * 128;
    const int bb = bh >> 4, h = bh & 15;
    const int tid = threadIdx.x, wave = tid >> 6, lane = tid & 63;
    const int quad = lane >> 4, l16 = lane & 15;
    __shared__ u16 lK[64 * 72];
    __shared__ u16 lV[64 * 72];
    __shared__ u16 lP[128 * 72];

    const int cn = cntb[bb];
    const int kEnd = (cn + 63) & ~63;

    bf16x8 aq[2][2];
    #pragma unroll
    for (int rg = 0; rg < 2; ++rg) {
        const int qrow = q0 + wave * 32 + rg * 16 + l16;
        const u16* qp = qb + (size_t)(bb * 1024 + qrow) * 1024 + h * 64 + quad * 8;
        aq[rg][0] = ldfrag(qp);
        aq[rg][1] = ldfrag(qp + 32);
    }

    f32x4 o[2][4] = {};
    float ps_acc[2][4] = {};

    const int srow = tid >> 3, scol = (tid & 7) * 8;
    const u16* kbase = kb + (size_t)(bb * 1024) * 1024 + h * 64 + scol;
    const u16* vbase = vb + (size_t)(bb * 1024) * 1024 + h * 64 + scol;

    u16x8 nk0 = *(const u16x8*)(kbase + (size_t)srow * 1024);
    u16x8 nk1 = *(const u16x8*)(kbase + (size_t)(srow + 32) * 1024);
    u16x8 nv0 = *(const u16x8*)(vbase + (size_t)srow * 1024);
    u16x8 nv1 = *(const u16x8*)(vbase + (size_t)(srow + 32) * 1024);

    const float C = 0.18033688011112043f;  // 0.125 * log2(e)

    for (int kt = 0; kt < kEnd; kt += 64) {
        __syncthreads();
        *(u16x8*)&lK[srow * 72 + scol] = nk0;
        *(u16x8*)&lK[(srow + 32) * 72 + scol] = nk1;
        #pragma unroll
        for (int j = 0; j < 8; ++j) {
            lV[(scol + j) * 72 + srow] = nv0[j];
            lV[(scol + j) * 72 + srow + 32] = nv1[j];
        }
        __syncthreads();
        const int ktn = kt + 64;
        if (ktn < kEnd) {
            nk0 = *(const u16x8*)(kbase + (size_t)(ktn + srow) * 1024);
            nk1 = *(const u16x8*)(kbase + (size_t)(ktn + srow + 32) * 1024);
            nv0 = *(const u16x8*)(vbase + (size_t)(ktn + srow) * 1024);
            nv1 = *(const u16x8*)(vbase + (size_t)(ktn + srow + 32) * 1024);
        }

        bf16x8 kf[4][2];
        #pragma unroll
        for (int n = 0; n < 4; ++n) {
            kf[n][0] = ldfrag(&lK[(n * 16 + l16) * 72 + quad * 8]);
            kf[n][1] = ldfrag(&lK[(n * 16 + l16) * 72 + 32 + quad * 8]);
        }
        f32x4 s[2][4];
        #pragma unroll
        for (int rg = 0; rg < 2; ++rg)
            #pragma unroll
            for (int n = 0; n < 4; ++n) {
                f32x4 t = {};
                t = mfma16(aq[rg][0], kf[n][0], t);
                t = mfma16(aq[rg][1], kf[n][1], t);
                s[rg][n] = t;
            }
        float bias[4];
        #pragma unroll
        for (int n = 0; n < 4; ++n)
            bias[n] = (kt + n * 16 + l16 < cn) ? 0.0f : -1e9f;
        #pragma unroll
        for (int rg = 0; rg < 2; ++rg)
            #pragma unroll
            for (int n = 0; n < 4; ++n)
                #pragma unroll
                for (int r = 0; r < 4; ++r) {
                    const float p =
                        __builtin_amdgcn_exp2f(__builtin_fmaf(s[rg][n][r], C, bias[n]));
                    ps_acc[rg][r] += p;
                    lP[(wave * 32 + rg * 16 + quad * 4 + r) * 72 + n * 16 + l16] =
                        f2bf_hw(p);
                }
        __asm__ __volatile__("s_waitcnt lgkmcnt(0)" ::: "memory");
        bf16x8 ap[2][2];
        #pragma unroll
        for (int rg = 0; rg < 2; ++rg) {
            ap[rg][0] = ldfrag(&lP[(wave * 32 + rg * 16 + l16) * 72 + quad * 8]);
            ap[rg][1] = ldfrag(&lP[(wave * 32 + rg * 16 + l16) * 72 + 32 + quad * 8]);
        }
        bf16x8 vf[4][2];
        #pragma unroll
        for (int ni = 0; ni < 4; ++ni) {
            vf[ni][0] = ldfrag(&lV[(ni * 16 + l16) * 72 + quad * 8]);
            vf[ni][1] = ldfrag(&lV[(ni * 16 + l16) * 72 + 32 + quad * 8]);
        }
        #pragma unroll
        for (int rg = 0; rg < 2; ++rg)
            #pragma unroll
            for (int ni = 0; ni < 4; ++ni) {
                o[rg][ni] = mfma16(ap[rg][0], vf[ni][0], o[rg][ni]);
                o[rg][ni] = mfma16(ap[rg][1], vf[ni][1], o[rg][ni]);
            }
    }
    #pragma unroll
    for (int off = 1; off < 16; off <<= 1)
        #pragma unroll
        for (int rg = 0; rg < 2; ++rg)
            #pragma unroll
            for (int r = 0; r < 4; ++r)
                ps_acc[rg][r] += __shfl_xor(ps_acc[rg][r], off);
    float rl[2][4];
    #pragma unroll
    for (int rg = 0; rg < 2; ++rg)
        #pragma unroll
        for (int r = 0; r < 4; ++r) rl[rg][r] = 1.f / ps_acc[rg][r];
    #pragma unroll
    for (int rg = 0; rg < 2; ++rg)
        #pragma unroll
        for (int ni = 0; ni < 4; ++ni)
            #pragma unroll
            for (int r = 0; r < 4; ++r) {
                const int row = q0 + wave * 32 + rg * 16 + quad * 4 + r;
                attb[(size_t)(bb * 1024 + row) * 1024 + h * 64 + ni * 16 + l16] =
                    f2bf_hw(o[rg][ni][r] * rl[rg][r]);
            }
}

// ---------- residual (bf16 y) + LayerNorm ----------
__global__ __launch_bounds__(256) void ln_res(const u16* __restrict__ ybf,
                                              const u16* __restrict__ xpb,
                                              const float* __restrict__ a2,
                                              const float* __restrict__ b2,
                                              float* __restrict__ out) {
    const int row = blockIdx.x, tid = threadIdx.x;
    const size_t base = (size_t)row * 1024;
    const int j = tid * 4;
    const u16x4 yv = *(const u16x4*)&ybf[base + j];
    const u16x4 xv = *(const u16x4*)&xpb[base + j];
    float x[4] = {bf2f(yv.x) + bf2f(xv.x), bf2f(yv.y) + bf2f(xv.y),
                  bf2f(yv.z) + bf2f(xv.z), bf2f(yv.w) + bf2f(xv.w)};
    float s = 0.f, ss = 0.f;
    #pragma unroll
    for (int i = 0; i < 4; ++i) { s += x[i]; ss += x[i] * x[i]; }
    #pragma unroll
    for (int off = 1; off < 64; off <<= 1) {
        s += __shfl_xor(s, off);
        ss += __shfl_xor(ss, off);
    }
    __shared__ float rs[4], rss[4];
    const int wave = tid >> 6, lane = tid & 63;
    if (lane == 0) { rs[wave] = s; rss[wave] = ss; }
    __syncthreads();
    s = rs[0] + rs[1] + rs[2] + rs[3];
    ss = rss[0] + rss[1] + rss[2] + rss[3];
    const float mean = s * (1.f / 1024.f);
    float var = (ss - s * mean) * (1.f / 1023.f);
    var = fmaxf(var, 0.f);
    const float inv = 1.f / (sqrtf(var) + 1e-6f);
    const float4 av = *(const float4*)&a2[j];
    const float4 bv = *(const float4*)&b2[j];
    float4 ov;
    ov.x = av.x * (x[0] - mean) * inv + bv.x;
    ov.y = av.y * (x[1] - mean) * inv + bv.y;
    ov.z = av.z * (x[2] - mean) * inv + bv.z;
    ov.w = av.w * (x[3] - mean) * inv + bv.w;
    *(float4*)&out[base + j] = ov;
}

extern "C" void kernel_launch(void* const* d_in, const int* in_sizes, int n_in,
                              void* d_out, int out_size, void* d_ws, size_t ws_size,
                              hipStream_t stream) {
    (void)in_sizes; (void)n_in; (void)out_size;
    const float* y   = (const float*)d_in[0];
    const int*   msk = (const int*)d_in[1];
    const float* Wq  = (const float*)d_in[2];
    const float* bq  = (const float*)d_in[3];
    const float* Wk  = (const float*)d_in[4];
    const float* bkb = (const float*)d_in[5];
    const float* Wv  = (const float*)d_in[6];
    const float* bv  = (const float*)d_in[7];
    const float* Wm  = (const float*)d_in[8];
    const float* bm  = (const float*)d_in[9];
    const float* a2  = (const float*)d_in[10];
    const float* b2  = (const float*)d_in[11];
    float* out = (float*)d_out;

    char* ws = (char*)d_ws;
    const size_t MB = 1u << 20;
    if (ws_size < 72 * MB) return;  // need 72 MB of scratch
    u16* yb  = (u16*)(ws);             // 16 MB, stays LIVE (ln_res reads it)
    u16* wqb = (u16*)(ws + 16 * MB);   // wq/wk/wv/wm contiguous (8 MB)
    u16* wmb = (u16*)(ws + 22 * MB);
    u16* qb  = (u16*)(ws + 24 * MB);   // 16 MB (reused as bf16 xp after attn)
    u16* kb  = (u16*)(ws + 40 * MB);   // 16 MB
    u16* vb  = (u16*)(ws + 56 * MB);   // 16 MB (attn reads it live)
    u16* xpb  = qb;   // qb dead after attn

    int* idxb = (int*)d_out;                       // 8 x 1024 ints
    int* cntb = idxb + 8192;                       // 8 ints
    u16* attb = (u16*)((char*)d_out + 16 * MB);    // 16 MB

    conv_all<<<12289, 256, 0, stream>>>(y, Wq, Wk, Wv, Wm, yb, wqb,
                                        msk, idxb, cntb);

    // Q + compacted-KV on the double-buffered legacy engine (4 blocks/CU)
    gemm_qkv<<<dim3(1536), 256, 0, stream>>>(
        yb, wqb, wqb + 1024 * 1024, bq, bkb, bv, qb, kb, vb, idxb, cntb);

    attn<<<dim3(1024), 256, 0, stream>>>(qb, kb, vb, cntb, attb);

    // M-proj on the same engine: grid 512 -> pure Q-type path (dense rows),
    // M=8192, N=1024, 4 blocks/CU, ~2 tiles/CU
    gemm_qkv<<<dim3(512), 256, 0, stream>>>(
        attb, wmb, wmb, bm, bm, bm, xpb, xpb, xpb, idxb, cntb);

    ln_res<<<8192, 256, 0, stream>>>(yb, xpb, a2, b2, out);
}